// Round 10
// baseline (104.866 us; speedup 1.0000x reference)
//
#include <hip/hip_runtime.h>
#include <math.h>

#define DCOL 8192
#define PNUM 1024
#define BATCH 256
#define HISTLEN 101
#define WIN 10
#define NK 5
#define EPSF 1e-6f
#define SLICES 8
#define SLICE_COLS (DCOL/SLICES)        // 1024
#define PPB 4                           // patterns per k1 block
#define BKK 32                          // k2 K-step

// ws layout (float offsets)
#define WS_RECENT 0                         // 10*8192            -> 81920
#define WS_RINV   (WIN*DCOL)                // 81920, 5*8192      -> 122880
#define WS_PSTR   (WS_RINV + NK*DCOL)       // 122880, 8*1024     -> 131072
#define WS_K2     (WS_PSTR + SLICES*PNUM)   // 131072, 50 floats
#define WS_PART   131584                    // split-K partials, spl*256*1024

typedef __attribute__((ext_vector_type(8))) short bf16x8;   // 8 bf16 = 4 VGPR
typedef __attribute__((ext_vector_type(4))) float f32x4;

__device__ inline short f2bf_s(float x) {               // RNE fp32->bf16 bits
  union { float f; unsigned u; } c; c.f = x;
  unsigned r = c.u + 0x7FFFu + ((c.u >> 16) & 1u);
  return (short)(r >> 16);
}
__device__ inline float bf2f_s(short b) {
  union { unsigned u; float f; } c; c.u = ((unsigned)(unsigned short)b) << 16;
  return c.f;
}

// ---------------------------------------------------------------------------
// K0: build `recent` (last 10 history rows with row hist_idx replaced by
// input_spikes[0]), rinv[k][d] = 1/(sqrt(sum_w K2[k][w]*recent^2)+eps),
// and the squared-kernel table k2 -> ws.
// ---------------------------------------------------------------------------
__global__ __launch_bounds__(256) void k0_prep(
    const float* __restrict__ spikes, const float* __restrict__ hist,
    const float* __restrict__ ck, const int* __restrict__ hidxp,
    float* __restrict__ ws)
{
  const int g = blockIdx.x * 256 + threadIdx.x;   // 0..2047
  const int col = g * 4;
  int hidx = hidxp[0] % HISTLEN;
  if (hidx < 0) hidx += HISTLEN;

  if (blockIdx.x == 0 && threadIdx.x < NK*WIN) {
    const float v = ck[threadIdx.x];
    ws[WS_K2 + threadIdx.x] = v * v;
  }

  float k2[NK][WIN];
#pragma unroll
  for (int k = 0; k < NK; ++k)
#pragma unroll
    for (int w = 0; w < WIN; ++w) { float v = ck[k*WIN + w]; k2[k][w] = v * v; }

  float rn[NK][4];
#pragma unroll
  for (int k = 0; k < NK; ++k)
#pragma unroll
    for (int j = 0; j < 4; ++j) rn[k][j] = 0.f;

#pragma unroll
  for (int w = 0; w < WIN; ++w) {
    const int row = HISTLEN - WIN + w;            // 91..100
    const float* src = (row == hidx) ? spikes : (hist + (size_t)row * DCOL);
    const float4 r = *(const float4*)(src + col);
    *(float4*)(ws + WS_RECENT + w*DCOL + col) = r;
    const float rr[4] = { r.x, r.y, r.z, r.w };
#pragma unroll
    for (int k = 0; k < NK; ++k)
#pragma unroll
      for (int j = 0; j < 4; ++j) rn[k][j] += k2[k][w] * rr[j] * rr[j];
  }

#pragma unroll
  for (int k = 0; k < NK; ++k) {
    float o[4];
#pragma unroll
    for (int j = 0; j < 4; ++j) o[j] = 1.0f / (sqrtf(rn[k][j]) + EPSF);
    float4 v; v.x = o[0]; v.y = o[1]; v.z = o[2]; v.w = o[3];
    *(float4*)(ws + WS_RINV + k*DCOL + col) = v;
  }
}

// ---------------------------------------------------------------------------
// K1: persistent blocks, grid = (8 slices, 256 pattern-groups), PPB=4.
// Loaded-latency queuing model: sustained BW = in-flight bytes / loaded
// latency. This version maximizes in-flight template bytes:
//  - ring depth 10 (= WIN): tp[w] at pattern pi refills row w of pattern
//    pi+1 -> ~10 KB outstanding per wave, no modulo, stream never drains
//    across pattern boundaries
//  - rinv read from LDS (staged once per block): epilogue uses ds_read
//    (lgkmcnt) -> never drains the vmcnt ring at pattern boundaries
//  - staging order: r+rinv loads, barrier (drains only those), ring init
// ---------------------------------------------------------------------------
__global__ __launch_bounds__(256) void k1_strength(
    const float* __restrict__ templ, const float* __restrict__ wk2,
    const float* __restrict__ recent, const float* __restrict__ rinv,
    float* __restrict__ pstr)
{
  __shared__ float sri[NK][SLICE_COLS];            // 20 KB
  __shared__ float red[PPB][4];
  const int sl  = blockIdx.x;
  const int p0  = blockIdx.y * PPB;
  const int tid = threadIdx.x;
  const int wid = tid >> 6;
  const int col = tid * 4;

  const float* __restrict__ tbase  = templ + (size_t)p0 * WIN * DCOL + sl*SLICE_COLS + col;
  const float* __restrict__ rbase  = recent + sl*SLICE_COLS + col;
  const float* __restrict__ ribase = rinv   + sl*SLICE_COLS + col;

  // once-per-block loads (L2-resident), then barrier BEFORE ring init so the
  // barrier's vmcnt(0) never touches the template ring.
  float4 r[WIN];
#pragma unroll
  for (int w = 0; w < WIN; ++w)
    r[w] = *(const float4*)(rbase + w*DCOL);
#pragma unroll
  for (int k = 0; k < NK; ++k)
    *(float4*)&sri[k][col] = *(const float4*)(ribase + k*DCOL);
  __syncthreads();

  // depth-10 template ring: slot w holds row w of the current pattern
  float4 tp[WIN];
#pragma unroll
  for (int w = 0; w < WIN; ++w)
    tp[w] = *(const float4*)(tbase + (size_t)w*DCOL);

#pragma unroll
  for (int pi = 0; pi < PPB; ++pi) {
    float nj[NK][4], tj[NK][4];
#pragma unroll
    for (int k = 0; k < NK; ++k)
#pragma unroll
      for (int j = 0; j < 4; ++j) { nj[k][j] = 0.f; tj[k][j] = 0.f; }

#pragma unroll
    for (int w = 0; w < WIN; ++w) {
      const float4 t4 = tp[w];
      if (pi + 1 < PPB)                            // refill: same row, next pattern
        tp[w] = *(const float4*)(tbase + (size_t)((pi+1)*WIN + w)*DCOL);
      const float4 r4 = r[w];
      const float x[4] = { r4.x*t4.x, r4.y*t4.y, r4.z*t4.z, r4.w*t4.w };
      const float y[4] = { t4.x*t4.x, t4.y*t4.y, t4.z*t4.z, t4.w*t4.w };
#pragma unroll
      for (int k = 0; k < NK; ++k) {
        const float cf = wk2[k*WIN + w];           // uniform -> s_load (lgkmcnt)
#pragma unroll
        for (int j = 0; j < 4; ++j) {
          nj[k][j] = fmaf(cf, x[j], nj[k][j]);
          tj[k][j] = fmaf(cf, y[j], tj[k][j]);
        }
      }
    }

    float acc[4] = {0.f, 0.f, 0.f, 0.f};
#pragma unroll
    for (int k = 0; k < NK; ++k) {
      const float4 ri4 = *(const float4*)&sri[k][col];   // ds_read, lgkmcnt only
      const float rik[4] = { ri4.x, ri4.y, ri4.z, ri4.w };
#pragma unroll
      for (int j = 0; j < 4; ++j)
        acc[j] += nj[k][j] * rik[j] * rsqrtf(tj[k][j]);
    }
    float a = acc[0] + acc[1] + acc[2] + acc[3];
#pragma unroll
    for (int off = 32; off > 0; off >>= 1) a += __shfl_down(a, off, 64);
    if ((tid & 63) == 0) red[pi][wid] = a;         // no barrier here
  }

  __syncthreads();                                 // single end-of-block barrier
  if (tid < PPB) {
    const float s = red[tid][0] + red[tid][1] + red[tid][2] + red[tid][3];
    pstr[sl*PNUM + p0 + tid] = s * (1.0f / (NK * DCOL));
  }
}

// ---------------------------------------------------------------------------
// K2: split-bf16 MFMA GEMM. C = A_hi*W_hi + A_hi*W_lo + A_lo*W_hi (lo*lo
// dropped, ~2^-18 rel). BM=256, BN=128, BK=32, 512 threads, spl split-K.
// grid = (spl, 8) = 256 blocks = exactly 1/CU at spl=32. (unchanged)
// ---------------------------------------------------------------------------
__global__ __launch_bounds__(512) void k2_mfma(
    const float* __restrict__ A, const float* __restrict__ Wt,
    float* __restrict__ part, const int ksub)
{
  __shared__ short Ah[4][256][8], Al[4][256][8];   // 16 KB each
  __shared__ short Wh[4][128][8], Wl[4][128][8];   // 8 KB each -> 48 KB total

  const int sk  = blockIdx.x;
  const int bn  = blockIdx.y;
  const int tid = threadIdx.x;          // 0..511
  const int lane = tid & 63;
  const int wid  = tid >> 6;            // 0..7
  const size_t k0 = (size_t)sk * ksub;

  const int srow = tid >> 3;            // 0..63
  const int skc  = (tid & 7) * 4;       // k offset 0..28
  const int skg  = skc >> 3;            // kgrp
  const int sko  = skc & 7;             // 0 or 4

  const float* Ap = A  + (size_t)srow * DCOL + k0 + skc;
  const float* Wp = Wt + (size_t)(bn*128 + srow) * DCOL + k0 + skc;

  f32x4 acc[2][8];
#pragma unroll
  for (int mt = 0; mt < 2; ++mt)
#pragma unroll
    for (int nt = 0; nt < 8; ++nt)
#pragma unroll
      for (int r = 0; r < 4; ++r) acc[mt][nt][r] = 0.f;

  const int niter = ksub / BKK;
  float4 ra[4], rw[2];
#pragma unroll
  for (int p = 0; p < 4; ++p) ra[p] = *(const float4*)(Ap + (size_t)(p*64)*DCOL);
#pragma unroll
  for (int p = 0; p < 2; ++p) rw[p] = *(const float4*)(Wp + (size_t)(p*64)*DCOL);

  for (int it = 0; it < niter; ++it) {
    __syncthreads();                     // prev mfma done reading LDS
#pragma unroll
    for (int p = 0; p < 4; ++p) {
      const float v[4] = { ra[p].x, ra[p].y, ra[p].z, ra[p].w };
      short h[4], l[4];
#pragma unroll
      for (int j = 0; j < 4; ++j) {
        h[j] = f2bf_s(v[j]);
        l[j] = f2bf_s(v[j] - bf2f_s(h[j]));
      }
      *(short4*)&Ah[skg][srow + p*64][sko] = make_short4(h[0],h[1],h[2],h[3]);
      *(short4*)&Al[skg][srow + p*64][sko] = make_short4(l[0],l[1],l[2],l[3]);
    }
#pragma unroll
    for (int p = 0; p < 2; ++p) {
      const float v[4] = { rw[p].x, rw[p].y, rw[p].z, rw[p].w };
      short h[4], l[4];
#pragma unroll
      for (int j = 0; j < 4; ++j) {
        h[j] = f2bf_s(v[j]);
        l[j] = f2bf_s(v[j] - bf2f_s(h[j]));
      }
      *(short4*)&Wh[skg][srow + p*64][sko] = make_short4(h[0],h[1],h[2],h[3]);
      *(short4*)&Wl[skg][srow + p*64][sko] = make_short4(l[0],l[1],l[2],l[3]);
    }
    __syncthreads();
    if (it + 1 < niter) {                // prefetch next K-step during mfma
#pragma unroll
      for (int p = 0; p < 4; ++p)
        ra[p] = *(const float4*)(Ap + (it+1)*BKK + (size_t)(p*64)*DCOL);
#pragma unroll
      for (int p = 0; p < 2; ++p)
        rw[p] = *(const float4*)(Wp + (it+1)*BKK + (size_t)(p*64)*DCOL);
    }

    const int frow = lane & 15;
    const int fkg  = lane >> 4;
    bf16x8 wfh[8], wfl[8];
#pragma unroll
    for (int nt = 0; nt < 8; ++nt) {
      wfh[nt] = *(const bf16x8*)&Wh[fkg][nt*16 + frow][0];
      wfl[nt] = *(const bf16x8*)&Wl[fkg][nt*16 + frow][0];
    }
    bf16x8 afh[2], afl[2];
#pragma unroll
    for (int mt = 0; mt < 2; ++mt) {
      afh[mt] = *(const bf16x8*)&Ah[fkg][wid*32 + mt*16 + frow][0];
      afl[mt] = *(const bf16x8*)&Al[fkg][wid*32 + mt*16 + frow][0];
    }
#pragma unroll
    for (int mt = 0; mt < 2; ++mt)
#pragma unroll
      for (int nt = 0; nt < 8; ++nt) {
        acc[mt][nt] = __builtin_amdgcn_mfma_f32_16x16x32_bf16(
            afh[mt], wfh[nt], acc[mt][nt], 0, 0, 0);
        acc[mt][nt] = __builtin_amdgcn_mfma_f32_16x16x32_bf16(
            afh[mt], wfl[nt], acc[mt][nt], 0, 0, 0);
        acc[mt][nt] = __builtin_amdgcn_mfma_f32_16x16x32_bf16(
            afl[mt], wfh[nt], acc[mt][nt], 0, 0, 0);
      }
  }

  float* pp = part + (size_t)sk * (BATCH * PNUM);
#pragma unroll
  for (int mt = 0; mt < 2; ++mt)
#pragma unroll
    for (int nt = 0; nt < 8; ++nt) {
      const int col = bn*128 + nt*16 + (lane & 15);
#pragma unroll
      for (int r = 0; r < 4; ++r) {
        const int row = wid*32 + mt*16 + (lane >> 4)*4 + r;
        pp[(size_t)row * PNUM + col] = acc[mt][nt][r];
      }
    }
}

// ---------------------------------------------------------------------------
// K3: out[b][p] = sigmoid(sum_sl pstr[sl][p] + sum_s partial[s][b][p])
// ---------------------------------------------------------------------------
__global__ __launch_bounds__(256) void k3_combine(
    const float* __restrict__ part, const float* __restrict__ pstr,
    float* __restrict__ out, const int spl)
{
  const int g = blockIdx.x * 256 + threadIdx.x;
  const int i4 = g * 4;
  const int p = i4 & (PNUM - 1);
  float acc[4] = {0.f, 0.f, 0.f, 0.f};
#pragma unroll
  for (int sl = 0; sl < SLICES; ++sl) {
    const float4 s4 = *(const float4*)(pstr + sl*PNUM + p);
    acc[0]+=s4.x; acc[1]+=s4.y; acc[2]+=s4.z; acc[3]+=s4.w;
  }
  for (int s = 0; s < spl; ++s) {
    const float4 v = *(const float4*)(part + (size_t)s * (BATCH*PNUM) + i4);
    acc[0]+=v.x; acc[1]+=v.y; acc[2]+=v.z; acc[3]+=v.w;
  }
  float4 o;
  o.x = 1.f / (1.f + __expf(-acc[0]));
  o.y = 1.f / (1.f + __expf(-acc[1]));
  o.z = 1.f / (1.f + __expf(-acc[2]));
  o.w = 1.f / (1.f + __expf(-acc[3]));
  *(float4*)(out + i4) = o;
}

extern "C" void kernel_launch(void* const* d_in, const int* in_sizes, int n_in,
                              void* d_out, int out_size, void* d_ws, size_t ws_size,
                              hipStream_t stream)
{
  const float* spikes = (const float*)d_in[0];   // (256, 8192)
  const float* hist   = (const float*)d_in[1];   // (101, 8192)
  const float* templ  = (const float*)d_in[2];   // (1024, 10, 8192)
  const float* wts    = (const float*)d_in[3];   // (1024, 8192)
  const float* ck     = (const float*)d_in[4];   // (5, 10)
  const int*   hidx   = (const int*)d_in[5];     // scalar
  float* ws  = (float*)d_ws;
  float* out = (float*)d_out;

  int spl = 32;                                   // split-K factor
  while (spl > 1 &&
         ws_size < ((size_t)WS_PART + (size_t)spl * BATCH * PNUM) * 4)
    spl >>= 1;
  const int ksub = DCOL / spl;                    // 256 at spl=32

  k0_prep<<<dim3(8), dim3(256), 0, stream>>>(spikes, hist, ck, hidx, ws);
  k1_strength<<<dim3(SLICES, PNUM/PPB), dim3(256), 0, stream>>>(
      templ, ws + WS_K2, ws + WS_RECENT, ws + WS_RINV, ws + WS_PSTR);
  k2_mfma<<<dim3(spl, PNUM/128), dim3(512), 0, stream>>>(
      spikes, wts, ws + WS_PART, ksub);
  k3_combine<<<dim3(BATCH*PNUM/(256*4)), dim3(256), 0, stream>>>(
      ws + WS_PART, ws + WS_PSTR, out, spl);
}